// Round 9
// baseline (722.295 us; speedup 1.0000x reference)
//
#include <hip/hip_runtime.h>

#define C_CLS 100000
#define D_DIM 512
#define B_ROWS 1024
#define K_KEEP 50000
#define EPS_F 1.1920929e-07f
#define MB_CT 32
#define BAND 2e-3f
#define DELTA 4e-4f
#define RMAX 32768

typedef short v8s __attribute__((ext_vector_type(8)));
typedef float v4f __attribute__((ext_vector_type(4)));

struct Ctrl { unsigned prefix; unsigned need; };

__device__ __forceinline__ unsigned key_of(float f){
  unsigned u = __float_as_uint(f);
  return (u & 0x80000000u) ? ~u : (u | 0x80000000u);
}
__device__ __forceinline__ float key_inv(unsigned k){
  unsigned u = (k & 0x80000000u) ? (k & 0x7FFFFFFFu) : ~k;
  return __uint_as_float(u);
}
__device__ __forceinline__ unsigned short f2bf_rne(float f){
  unsigned u = __float_as_uint(f);
  unsigned r = (u + 0x7FFFu + ((u >> 16) & 1u)) >> 16;
  return (unsigned short)r;
}
__device__ __forceinline__ float bf2f(unsigned short h){
  return __uint_as_float(((unsigned)h) << 16);
}

// Packed tn layout (SEPARATE hi/lo buffers — measured-fast config):
// tile t = (b & ~15) + (k>>5), 512 shorts/tile; element (b&15, kk=k&31) at
// t*512 + (kk>>3)*128 + (b&15)*8 + (kk&7). MFMA A-frag reads v8s at t*512 + lane*8.

// ---------------- normalize tensor rows + packed bf16 hi/lo split + target scatter ----------------
__global__ __launch_bounds__(64) void norm_t_kernel(const float* __restrict__ t, float* __restrict__ tn,
                                                    unsigned short* __restrict__ tnph, unsigned short* __restrict__ tnpl,
                                                    const int* __restrict__ tgt, unsigned* __restrict__ keys){
  int row = blockIdx.x, lane = threadIdx.x;
  if (lane == 0) atomicMax(&keys[tgt[row]], key_of(2.0f));
  const float4* p = (const float4*)(t + (size_t)row * D_DIM);
  float4 a = p[lane*2+0], b = p[lane*2+1];
  float s = a.x*a.x + a.y*a.y + a.z*a.z + a.w*a.w
          + b.x*b.x + b.y*b.y + b.z*b.z + b.w*b.w;
  #pragma unroll
  for (int off = 32; off; off >>= 1) s += __shfl_xor(s, off);
  float den = fmaxf(sqrtf(s), EPS_F);
  float o[8] = {a.x/den, a.y/den, a.z/den, a.w/den, b.x/den, b.y/den, b.z/den, b.w/den};
  float4* q = (float4*)(tn + (size_t)row * D_DIM);
  q[lane*2+0] = make_float4(o[0],o[1],o[2],o[3]);
  q[lane*2+1] = make_float4(o[4],o[5],o[6],o[7]);
  v8s hv, lv;
  #pragma unroll
  for (int j = 0; j < 8; ++j){
    unsigned short h = f2bf_rne(o[j]);
    hv[j] = (short)h;
    lv[j] = (short)f2bf_rne(o[j] - bf2f(h));
  }
  size_t di = (size_t)((row & ~15) + (lane >> 2)) * 512 + (lane & 3) * 128 + (row & 15) * 8;
  *(v8s*)(tnph + di) = hv;
  *(v8s*)(tnpl + di) = lv;
}

__device__ __forceinline__ void load_a2(const unsigned short* __restrict__ tp, int b0, int ks, int lane, v8s* dst){
  #pragma unroll
  for (int i = 0; i < 2; ++i){
    int t = b0 + i*16 + (ks >> 5);
    dst[i] = *(const v8s*)(tp + (size_t)t * 512 + lane * 8);
  }
}

// ---------------- MFMA mining (2-product bf16x2, 32 classes/block, 512 threads): ----------------
// Round-9: MB_CT=32 -> LDS 33KB -> 4 blocks/CU x 8 waves = 8 waves/SIMD.
// Ladder evidence (R0-R8): MfmaUtil tracks waves/SIMD ONLY (2w->24%, 4w->30%) across 2x/4x
// A-traffic changes, unrolls, sched_barriers, DMA — latency hidden by TLP alone.
// This is the untried 8-waves/SIMD rung. launch_bounds(512,8) caps VGPR at 64
// (R5 measured 56 with 2x this accumulator state -> fits). A-traffic 6.4GB ~ 26TB/s < L2 34.5.
// NO nontemporal hints (round-1: nt on S cost +266us via head_copy/refine going cold).
__global__ __launch_bounds__(512, 8) void mine_kernel(
    const unsigned short* __restrict__ tnph, const unsigned short* __restrict__ tnpl,
    const float* __restrict__ w, unsigned* __restrict__ keys,
    float* __restrict__ S, float* __restrict__ winv_g){
  __shared__ unsigned short lw[MB_CT * D_DIM];  // 32 KB, w hi, swizzled
  __shared__ float wn[MB_CT];
  const int tid = threadIdx.x;
  const int lane = tid & 63;
  const int cb = blockIdx.x * MB_CT;
  // stage w rows (hi only); one row per wave per pass -> free norm reduce
  #pragma unroll
  for (int st = 0; st < 4; ++st){
    int g = tid + st * 512;
    int row = g >> 6, fc = g & 63;   // fc == lane
    int c = cb + row; if (c >= C_CLS) c = C_CLS - 1;
    const float4* src = (const float4*)(w + (size_t)c * D_DIM + fc * 8);
    float4 v0 = src[0], v1 = src[1];
    float vv[8] = {v0.x,v0.y,v0.z,v0.w,v1.x,v1.y,v1.z,v1.w};
    float s = 0.f;
    #pragma unroll
    for (int off = 32; off; off >>= 1){} // (kept structure minimal; reduce below)
    s = 0.f;
    #pragma unroll
    for (int j = 0; j < 8; ++j) s += vv[j]*vv[j];
    #pragma unroll
    for (int off = 32; off; off >>= 1) s += __shfl_xor(s, off);
    if (lane == 0) wn[row] = 1.0f / fmaxf(sqrtf(s), EPS_F);
    v8s hv;
    #pragma unroll
    for (int j = 0; j < 8; ++j) hv[j] = (short)f2bf_rne(vv[j]);
    int csw = fc ^ (row & 7);
    *(v8s*)&lw[(size_t)row * D_DIM + csw * 8] = hv;
  }
  __syncthreads();
  if (tid < MB_CT && cb + tid < C_CLS) winv_g[cb + tid] = wn[tid];

  const int wv = tid >> 6;
  const int lr = lane & 15, lg = lane >> 4;
  const int bbase = wv * 128;
  float runmax[2] = {-1e30f,-1e30f};
  v4f acc[2][2];
  #pragma unroll
  for (int j = 0; j < 2; ++j)
    #pragma unroll
    for (int i = 0; i < 2; ++i) acc[j][i] = (v4f){0.f,0.f,0.f,0.f};

  v8s cah[2], cal[2];
  load_a2(tnph, bbase, 0, lane, cah);
  load_a2(tnpl, bbase, 0, lane, cal);

  for (int it = 0; it < 64; ++it){
    const int chunk = it >> 4, ks = (it & 15) << 5;
    const int b0 = bbase + chunk * 32;
    v8s nah[2], nal[2];
    if (it < 63){
      int nit = it + 1;
      int nb0 = bbase + (nit >> 4) * 32, nks = (nit & 15) << 5;
      load_a2(tnph, nb0, nks, lane, nah);
      load_a2(tnpl, nb0, nks, lane, nal);
    }
    v8s bh[2];
    #pragma unroll
    for (int j = 0; j < 2; ++j){
      int row = j*16 + lr;
      int ch = ((ks >> 3) + lg) ^ (lr & 7);
      bh[j] = *(const v8s*)&lw[(size_t)row * D_DIM + ch * 8];
    }
    #pragma unroll
    for (int j = 0; j < 2; ++j)
      #pragma unroll
      for (int i = 0; i < 2; ++i){
        acc[j][i] = __builtin_amdgcn_mfma_f32_16x16x32_bf16(cah[i], bh[j], acc[j][i], 0, 0, 0);
        acc[j][i] = __builtin_amdgcn_mfma_f32_16x16x32_bf16(cal[i], bh[j], acc[j][i], 0, 0, 0);
      }
    if ((it & 15) == 15){
      #pragma unroll
      for (int j = 0; j < 2; ++j){
        float m = acc[j][0][0];
        #pragma unroll
        for (int i = 0; i < 2; ++i)
          #pragma unroll
          for (int r = 0; r < 4; ++r) m = fmaxf(m, acc[j][i][r]);
        runmax[j] = fmaxf(runmax[j], m);
        int cls = cb + j*16 + lr;
        if (cls < C_CLS){
          #pragma unroll
          for (int i = 0; i < 2; ++i){
            float4 v = make_float4(acc[j][i][0], acc[j][i][1], acc[j][i][2], acc[j][i][3]);
            *(float4*)(S + (size_t)cls * B_ROWS + b0 + i*16 + lg*4) = v;
          }
        }
        #pragma unroll
        for (int i = 0; i < 2; ++i) acc[j][i] = (v4f){0.f,0.f,0.f,0.f};
      }
    }
    if (it < 63){
      #pragma unroll
      for (int i = 0; i < 2; ++i){ cah[i] = nah[i]; cal[i] = nal[i]; }
    }
  }
  #pragma unroll
  for (int j = 0; j < 2; ++j){
    float m = runmax[j];
    m = fmaxf(m, __shfl_xor(m, 16));
    m = fmaxf(m, __shfl_xor(m, 32));
    int cls = cb + j*16 + lr;
    if (lg == 0 && cls < C_CLS)
      atomicMax(&keys[cls], key_of(m * wn[j*16 + lr]));
  }
}

// ---------------- fused radix pass: LDS hist -> global -> last block selects ----------------
__global__ __launch_bounds__(256) void histsel_kernel(const unsigned* __restrict__ keys, unsigned* __restrict__ hist,
                                                      unsigned* __restrict__ done, Ctrl* __restrict__ ctrl, int shift){
  __shared__ unsigned h[256];
  __shared__ int lastf;
  int t = threadIdx.x;
  h[t] = 0u;
  __syncthreads();
  unsigned himask = (shift >= 24) ? 0u : (0xFFFFFFFFu << (shift + 8));
  unsigned prefix = (shift == 24) ? 0u : (ctrl->prefix & himask);
  for (int c = blockIdx.x * 256 + t; c < C_CLS; c += gridDim.x * 256){
    unsigned k = keys[c];
    if ((k & himask) == prefix) atomicAdd(&h[(k >> shift) & 255], 1u);
  }
  __syncthreads();
  if (h[t]) atomicAdd(&hist[t], h[t]);
  __threadfence();
  if (t == 0) lastf = (atomicAdd(done, 1u) == (unsigned)(gridDim.x - 1));
  __syncthreads();
  if (lastf){
    unsigned v = __hip_atomic_load(&hist[t], __ATOMIC_RELAXED, __HIP_MEMORY_SCOPE_AGENT);
    h[t] = v;
    __syncthreads();
    if (t == 0){
      unsigned need = (shift == 24) ? (unsigned)K_KEEP : ctrl->need;
      unsigned pfx  = (shift == 24) ? 0u : ctrl->prefix;
      unsigned cum = 0; int b;
      for (b = 255; b >= 0; --b){
        if (cum + h[b] >= need) break;
        cum += h[b];
      }
      if (b < 0) b = 0;
      ctrl->prefix = pfx | ((unsigned)b << shift);
      ctrl->need = need - cum;
      __hip_atomic_store(done, 0u, __ATOMIC_RELAXED, __HIP_MEMORY_SCOPE_AGENT);
    }
    __hip_atomic_store(&hist[t], 0u, __ATOMIC_RELAXED, __HIP_MEMORY_SCOPE_AGENT);
  }
}

// ---------------- boundary band around exact screened threshold ----------------
__global__ void band_kernel(const unsigned* __restrict__ keys, const Ctrl* __restrict__ ctrl,
                            int* __restrict__ rlist, int* __restrict__ rcount){
  int c = blockIdx.x * 256 + threadIdx.x;
  if (c >= C_CLS) return;
  unsigned k = keys[c];
  if (k == key_of(2.0f)) return;
  float t = key_inv(ctrl->prefix);
  if (fabsf(key_inv(k) - t) <= BAND){
    int i = atomicAdd(rcount, 1);
    if (i < RMAX) rlist[i] = c;
  }
}

// ---------------- refine via fp32 S candidate rows: exact fp64 dot only where needed ----------------
__global__ __launch_bounds__(256) void refine_kernel(
    const float* __restrict__ tn, const float* __restrict__ w,
    const float* __restrict__ winv, const float* __restrict__ S,
    const int* __restrict__ rlist, const int* __restrict__ rcount,
    unsigned* __restrict__ keys){
  __shared__ float red[256];
  __shared__ double dred[256];
  __shared__ int cand[32];
  __shared__ int ncand;
  int n = *rcount; if (n > RMAX) n = RMAX;
  int t = threadIdx.x;
  for (int i = blockIdx.x; i < n; i += gridDim.x){
    int c = rlist[i];
    const v4f* srow = (const v4f*)(S + (size_t)c * B_ROWS);
    v4f sv = srow[t];
    float m = fmaxf(fmaxf(sv[0],sv[1]), fmaxf(sv[2],sv[3]));
    red[t] = m; __syncthreads();
    for (int off2 = 128; off2; off2 >>= 1){
      if (t < off2) red[t] = fmaxf(red[t], red[t+off2]);
      __syncthreads();
    }
    float thr = red[0] - DELTA;
    if (t == 0) ncand = 0;
    __syncthreads();
    #pragma unroll
    for (int e = 0; e < 4; ++e){
      if (sv[e] >= thr){
        int ci = atomicAdd(&ncand, 1);
        if (ci < 32) cand[ci] = t*4 + e;
      }
    }
    __syncthreads();
    int nc = ncand; if (nc > 32) nc = 32;
    const float* wrow = w + (size_t)c * D_DIM;
    double w0 = (double)wrow[2*t], w1 = (double)wrow[2*t+1];
    double best = -1e300;
    for (int q = 0; q < nc; ++q){
      int b = cand[q];
      const float* tr = tn + (size_t)b * D_DIM;
      double p = fma((double)tr[2*t], w0, (double)tr[2*t+1] * w1);
      dred[t] = p; __syncthreads();
      for (int off2 = 128; off2; off2 >>= 1){
        if (t < off2) dred[t] += dred[t+off2];
        __syncthreads();
      }
      if (t == 0) best = fmax(best, dred[0]);
      __syncthreads();
    }
    if (t == 0) keys[c] = key_of((float)(best * (double)winv[c]));
    __syncthreads();
  }
}

// ---------------- (gt,eq)-pair scan: block sums + last-block mid-scan ----------------
__global__ __launch_bounds__(256) void scanA_kernel(const unsigned* __restrict__ keys, const Ctrl* __restrict__ ctrl,
                                                    uint2* __restrict__ bsum2, unsigned* __restrict__ done2, int nb){
  __shared__ unsigned red[256];
  __shared__ int lastf;
  int t = threadIdx.x;
  unsigned T = ctrl->prefix;
  int base = blockIdx.x * 1024 + t * 4;
  unsigned pack = 0;
  #pragma unroll
  for (int j = 0; j < 4; ++j){
    int c = base + j;
    if (c < C_CLS){
      unsigned k = keys[c];
      if (k > T) pack += 0x10000u;
      else if (k == T) pack += 1u;
    }
  }
  red[t] = pack; __syncthreads();
  for (int off = 128; off; off >>= 1){
    if (t < off) red[t] += red[t + off];
    __syncthreads();
  }
  if (t == 0) bsum2[blockIdx.x] = make_uint2(red[0] >> 16, red[0] & 0xFFFFu);
  __threadfence();
  if (t == 0) lastf = (atomicAdd(done2, 1u) == (unsigned)(gridDim.x - 1));
  __syncthreads();
  if (lastf && t == 0){
    unsigned rg = 0, re = 0;
    for (int i = 0; i < nb; ++i){
      unsigned vx = __hip_atomic_load(&bsum2[i].x, __ATOMIC_RELAXED, __HIP_MEMORY_SCOPE_AGENT);
      unsigned vy = __hip_atomic_load(&bsum2[i].y, __ATOMIC_RELAXED, __HIP_MEMORY_SCOPE_AGENT);
      __hip_atomic_store(&bsum2[i].x, rg, __ATOMIC_RELAXED, __HIP_MEMORY_SCOPE_AGENT);
      __hip_atomic_store(&bsum2[i].y, re, __ATOMIC_RELAXED, __HIP_MEMORY_SCOPE_AGENT);
      rg += vx; re += vy;
    }
    __hip_atomic_store(done2, 0u, __ATOMIC_RELAXED, __HIP_MEMORY_SCOPE_AGENT);
  }
}

// selected = gt | (eq & eqrank<need); pos = gt_excl + min(eq_excl, need); scatter sel ascending
__global__ __launch_bounds__(256) void scanC_kernel(const unsigned* __restrict__ keys, const Ctrl* __restrict__ ctrl,
                                                    const uint2* __restrict__ bsum2, unsigned* __restrict__ pos,
                                                    int* __restrict__ sel){
  __shared__ unsigned ls[256];
  int t = threadIdx.x;
  unsigned T = ctrl->prefix, need = ctrl->need;
  int base = blockIdx.x * 1024 + t * 4;
  unsigned gtv[4], eqv[4], pack = 0;
  #pragma unroll
  for (int j = 0; j < 4; ++j){
    int c = base + j;
    unsigned k = (c < C_CLS) ? keys[c] : 0u;
    gtv[j] = (c < C_CLS && k > T) ? 1u : 0u;
    eqv[j] = (c < C_CLS && k == T) ? 1u : 0u;
    pack += (gtv[j] << 16) + eqv[j];
  }
  ls[t] = pack; __syncthreads();
  for (int off = 1; off < 256; off <<= 1){
    unsigned v = (t >= off) ? ls[t - off] : 0u;
    __syncthreads();
    ls[t] += v;
    __syncthreads();
  }
  unsigned excl = ls[t] - pack;
  uint2 bs = bsum2[blockIdx.x];
  unsigned gtx = bs.x + (excl >> 16);
  unsigned eqx = bs.y + (excl & 0xFFFFu);
  #pragma unroll
  for (int j = 0; j < 4; ++j){
    int c = base + j;
    if (c < C_CLS){
      unsigned p = gtx + (eqx < need ? eqx : need);
      pos[c] = p;
      if (gtv[j] || (eqv[j] && eqx < need)) sel[p] = c;
      gtx += gtv[j]; eqx += eqv[j];
    }
  }
}

__global__ void ntgt_kernel(const int* __restrict__ tgt, const unsigned* __restrict__ pos, float* __restrict__ out){
  int b = blockIdx.x * 256 + threadIdx.x;
  if (b < B_ROWS) out[(size_t)B_ROWS * K_KEEP + b] = (float)pos[tgt[b]];
}

// ---------------- head: gather-transpose-scale from fp32 S ----------------
// Round-5 config (best measured ~235us): 64x64 tile, 8 blocks/CU, full-row lane mapping
// (16 lanes per row) in both phases; grid x = b-tile (fastest) for S-row L2/L3 reuse.
// Round-6's 128-k tile (4 blocks/CU) regressed +23us — occupancy dominates here.
__global__ __launch_bounds__(256) void head_copy_kernel(const float* __restrict__ S, const float* __restrict__ winv,
                                                        const int* __restrict__ sel, float* __restrict__ out){
  __shared__ float tile[64][68];
  __shared__ float wsc[64];
  int k0 = blockIdx.y * 64;
  int b0 = blockIdx.x * 64;
  int tid = threadIdx.x;
  int nk = K_KEEP - k0; if (nk > 64) nk = 64;
  if (tid < 64){
    int kk = k0 + tid;
    wsc[tid] = (kk < K_KEEP) ? winv[sel[kk]] : 0.f;
  }
  int r = tid >> 4, lq = tid & 15;
  #pragma unroll
  for (int itr = 0; itr < 4; ++itr){
    int i = itr * 16 + r;
    if (i < nk){
      int c = sel[k0 + i];
      float4 v = *(const float4*)(S + (size_t)c * B_ROWS + b0 + lq * 4);
      *(float4*)&tile[i][lq * 4] = v;
    }
  }
  __syncthreads();
  #pragma unroll
  for (int itw = 0; itw < 4; ++itw){
    int bb = itw * 16 + r;
    int kk = lq * 4;
    size_t obase = (size_t)(b0 + bb) * K_KEEP + k0;
    if (kk + 3 < nk){
      float4 v = make_float4(tile[kk+0][bb]*wsc[kk+0], tile[kk+1][bb]*wsc[kk+1],
                             tile[kk+2][bb]*wsc[kk+2], tile[kk+3][bb]*wsc[kk+3]);
      *(float4*)(out + obase + kk) = v;
    } else {
      for (int e = 0; e < 4; ++e)
        if (kk + e < nk) out[obase + kk + e] = tile[kk+e][bb]*wsc[kk+e];
    }
  }
}

extern "C" void kernel_launch(void* const* d_in, const int* in_sizes, int n_in,
                              void* d_out, int out_size, void* d_ws, size_t ws_size,
                              hipStream_t stream){
  const float* tensor = (const float*)d_in[0];
  const int*   target = (const int*)d_in[1];
  const float* weight = (const float*)d_in[2];
  float* out = (float*)d_out;

  char* ws = (char*)d_ws;
  size_t off = 0;
  auto carve = [&](size_t bytes) -> char* {
    char* p = ws + off;
    off = (off + bytes + 511) & ~(size_t)511;
    return p;
  };
  float*          tn   = (float*)carve((size_t)B_ROWS * D_DIM * 4);
  unsigned short* tnph = (unsigned short*)carve((size_t)B_ROWS * D_DIM * 2);
  unsigned short* tnpl = (unsigned short*)carve((size_t)B_ROWS * D_DIM * 2);
  float*          winv = (float*)carve((size_t)C_CLS * 4);
  size_t zs = off;  // ---- zeroed region start ----
  unsigned* keys   = (unsigned*)carve((size_t)C_CLS * 4);
  unsigned* hist   = (unsigned*)carve(256 * 4);
  unsigned* done   = (unsigned*)carve(64);
  unsigned* done2  = (unsigned*)carve(64);
  int*      rcount = (int*)carve(64);
  size_t ze = off;  // ---- zeroed region end ----
  Ctrl*     ctrl   = (Ctrl*)carve(64);
  uint2*    bsum2  = (uint2*)carve(128 * 8);
  int*      rlist  = (int*)carve((size_t)RMAX * 4);
  unsigned* pos    = (unsigned*)carve((size_t)C_CLS * 4);
  int*      sel    = (int*)carve((size_t)K_KEEP * 4);
  float*    S      = (float*)carve((size_t)C_CLS * B_ROWS * 4);
  (void)in_sizes; (void)n_in; (void)out_size; (void)ws_size;

  hipMemsetAsync(ws + zs, 0, ze - zs, stream);

  norm_t_kernel<<<B_ROWS, 64, 0, stream>>>(tensor, tn, tnph, tnpl, target, keys);

  mine_kernel<<<(C_CLS + MB_CT - 1) / MB_CT, 512, 0, stream>>>(tnph, tnpl, weight, keys, S, winv);

  // round A: exact screened threshold (4 passes)
  for (int shift = 24; shift >= 0; shift -= 8)
    histsel_kernel<<<128, 256, 0, stream>>>(keys, hist, done, ctrl, shift);

  band_kernel<<<(C_CLS + 255) / 256, 256, 0, stream>>>(keys, ctrl, rlist, rcount);
  refine_kernel<<<2048, 256, 0, stream>>>(tn, weight, winv, S, rlist, rcount, keys);

  // round B: exact threshold on refined keys
  for (int shift = 24; shift >= 0; shift -= 8)
    histsel_kernel<<<128, 256, 0, stream>>>(keys, hist, done, ctrl, shift);

  const int nb = (C_CLS + 1023) / 1024;  // 98
  scanA_kernel<<<nb, 256, 0, stream>>>(keys, ctrl, bsum2, done2, nb);
  scanC_kernel<<<nb, 256, 0, stream>>>(keys, ctrl, bsum2, pos, sel);

  ntgt_kernel<<<(B_ROWS + 255) / 256, 256, 0, stream>>>(target, pos, out);
  head_copy_kernel<<<dim3(B_ROWS / 64, (K_KEEP + 63) / 64), 256, 0, stream>>>(S, winv, sel, out);
}

// Round 10
// 612.976 us; speedup vs baseline: 1.1783x; 1.1783x over previous
//
#include <hip/hip_runtime.h>

#define C_CLS 100000
#define D_DIM 512
#define B_ROWS 1024
#define K_KEEP 50000
#define EPS_F 1.1920929e-07f
#define MB_CT 64
#define BAND 2e-3f
#define DELTA 4e-4f
#define RMAX 32768

typedef short v8s __attribute__((ext_vector_type(8)));
typedef float v4f __attribute__((ext_vector_type(4)));

struct Ctrl { unsigned prefix; unsigned need; };

__device__ __forceinline__ unsigned key_of(float f){
  unsigned u = __float_as_uint(f);
  return (u & 0x80000000u) ? ~u : (u | 0x80000000u);
}
__device__ __forceinline__ float key_inv(unsigned k){
  unsigned u = (k & 0x80000000u) ? (k & 0x7FFFFFFFu) : ~k;
  return __uint_as_float(u);
}
__device__ __forceinline__ unsigned short f2bf_rne(float f){
  unsigned u = __float_as_uint(f);
  unsigned r = (u + 0x7FFFu + ((u >> 16) & 1u)) >> 16;
  return (unsigned short)r;
}
__device__ __forceinline__ float bf2f(unsigned short h){
  return __uint_as_float(((unsigned)h) << 16);
}

// Packed tn layout (SEPARATE hi/lo buffers — measured-fast config):
// tile t = (b & ~15) + (k>>5), 512 shorts/tile; element (b&15, kk=k&31) at
// t*512 + (kk>>3)*128 + (b&15)*8 + (kk&7). MFMA A-frag reads v8s at t*512 + lane*8.

// ---------------- normalize tensor rows + packed bf16 hi/lo split + target scatter ----------------
__global__ __launch_bounds__(64) void norm_t_kernel(const float* __restrict__ t, float* __restrict__ tn,
                                                    unsigned short* __restrict__ tnph, unsigned short* __restrict__ tnpl,
                                                    const int* __restrict__ tgt, unsigned* __restrict__ keys){
  int row = blockIdx.x, lane = threadIdx.x;
  if (lane == 0) atomicMax(&keys[tgt[row]], key_of(2.0f));
  const float4* p = (const float4*)(t + (size_t)row * D_DIM);
  float4 a = p[lane*2+0], b = p[lane*2+1];
  float s = a.x*a.x + a.y*a.y + a.z*a.z + a.w*a.w
          + b.x*b.x + b.y*b.y + b.z*b.z + b.w*b.w;
  #pragma unroll
  for (int off = 32; off; off >>= 1) s += __shfl_xor(s, off);
  float den = fmaxf(sqrtf(s), EPS_F);
  float o[8] = {a.x/den, a.y/den, a.z/den, a.w/den, b.x/den, b.y/den, b.z/den, b.w/den};
  float4* q = (float4*)(tn + (size_t)row * D_DIM);
  q[lane*2+0] = make_float4(o[0],o[1],o[2],o[3]);
  q[lane*2+1] = make_float4(o[4],o[5],o[6],o[7]);
  v8s hv, lv;
  #pragma unroll
  for (int j = 0; j < 8; ++j){
    unsigned short h = f2bf_rne(o[j]);
    hv[j] = (short)h;
    lv[j] = (short)f2bf_rne(o[j] - bf2f(h));
  }
  size_t di = (size_t)((row & ~15) + (lane >> 2)) * 512 + (lane & 3) * 128 + (row & 15) * 8;
  *(v8s*)(tnph + di) = hv;
  *(v8s*)(tnpl + di) = lv;
}

__device__ __forceinline__ void load_a2(const unsigned short* __restrict__ tp, int b0, int ks, int lane, v8s* dst){
  #pragma unroll
  for (int i = 0; i < 2; ++i){
    int t = b0 + i*16 + (ks >> 5);
    dst[i] = *(const v8s*)(tp + (size_t)t * 512 + lane * 8);
  }
}

// ---------------- MFMA mining (2-product bf16x2, 64 classes/block, 512 threads): ----------------
// R5-best config: 8 waves x 128 b each, LDS 66KB -> 2 blocks/CU = 4 waves/SIMD.
// Round-10 change: lw stored in PACKED-TILE layout (64 tiles x 512 shorts, tile =
// (c>>4)*16 + (k>>5)) with per-tile XOR m=(t&1)*4+kslot. The old row-major lw made
// every bh ds_read_b128 a ~4-8-way bank conflict (bank = ch%8 only; lanes lr/lr+8
// collide; SQ_LDS_BANK_CONFLICT pinned at 12.8M for 9 rounds; LDS-serialized cost
// ~186us/CU > 101us MFMA floor = the ~30% MfmaUtil wall). New layout: bh reads are
// permuted-contiguous 256B per 16-lane phase (conflict-free); staging writes 2-way (free).
// NO nontemporal hints (round-1: nt on S cost +266us via head_copy/refine going cold).
__global__ __launch_bounds__(512, 4) void mine_kernel(
    const unsigned short* __restrict__ tnph, const unsigned short* __restrict__ tnpl,
    const float* __restrict__ w, unsigned* __restrict__ keys,
    float* __restrict__ S, float* __restrict__ winv_g){
  __shared__ unsigned short lw[MB_CT * D_DIM];  // 64 KB: 64 tiles x 512 shorts, hi only
  __shared__ float wn[MB_CT];
  const int tid = threadIdx.x;
  const int lane = tid & 63;
  const int cb = blockIdx.x * MB_CT;
  // stage w rows (hi only); each wave handles one row per pass -> free norm reduce
  #pragma unroll
  for (int st = 0; st < 8; ++st){
    int g = tid + st * 512;
    int row = g >> 6, fc = g & 63;   // fc == lane
    int c = cb + row; if (c >= C_CLS) c = C_CLS - 1;
    const float4* src = (const float4*)(w + (size_t)c * D_DIM + fc * 8);
    float4 v0 = src[0], v1 = src[1];
    float vv[8] = {v0.x,v0.y,v0.z,v0.w,v1.x,v1.y,v1.z,v1.w};
    float s = 0.f;
    #pragma unroll
    for (int j = 0; j < 8; ++j) s += vv[j]*vv[j];
    #pragma unroll
    for (int off = 32; off; off >>= 1) s += __shfl_xor(s, off);
    if (lane == 0) wn[row] = 1.0f / fmaxf(sqrtf(s), EPS_F);
    v8s hv;
    #pragma unroll
    for (int j = 0; j < 8; ++j) hv[j] = (short)f2bf_rne(vv[j]);
    // packed-tile write: element block (c&15, k=fc*8..fc*8+7)
    // tile t = (c>>4)*16 + (fc>>2); kslot = fc&3; m = (t&1)*4 + kslot
    int t = (row >> 4) * 16 + (fc >> 2);
    int kslot = fc & 3;
    int m = ((fc >> 2) & 1) * 4 + kslot;
    int a16 = t * 64 + kslot * 16 + ((row & 15) ^ m);
    *(v8s*)&lw[(size_t)a16 * 8] = hv;
  }
  __syncthreads();
  if (tid < MB_CT && cb + tid < C_CLS) winv_g[cb + tid] = wn[tid];

  const int wv = tid >> 6;
  const int lr = lane & 15, lg = lane >> 4;
  const int bbase = wv * 128;
  float runmax[4] = {-1e30f,-1e30f,-1e30f,-1e30f};
  v4f acc[4][2];
  #pragma unroll
  for (int j = 0; j < 4; ++j)
    #pragma unroll
    for (int i = 0; i < 2; ++i) acc[j][i] = (v4f){0.f,0.f,0.f,0.f};

  v8s cah[2], cal[2];
  load_a2(tnph, bbase, 0, lane, cah);
  load_a2(tnpl, bbase, 0, lane, cal);

  for (int it = 0; it < 64; ++it){
    const int chunk = it >> 4, kt = it & 15;
    const int b0 = bbase + chunk * 32;
    v8s nah[2], nal[2];
    if (it < 63){
      int nit = it + 1;
      int nb0 = bbase + (nit >> 4) * 32, nks = (nit & 15) << 5;
      load_a2(tnph, nb0, nks, lane, nah);
      load_a2(tnpl, nb0, nks, lane, nal);
    }
    v8s bh[4];
    {
      int m = (kt & 1) * 4 + lg;
      int ci = (lr ^ m);          // m<=7, lr<=15 -> ci in 0..15
      #pragma unroll
      for (int j = 0; j < 4; ++j){
        int t = j * 16 + kt;
        int a16 = t * 64 + lg * 16 + ci;
        bh[j] = *(const v8s*)&lw[(size_t)a16 * 8];
      }
    }
    #pragma unroll
    for (int j = 0; j < 4; ++j)
      #pragma unroll
      for (int i = 0; i < 2; ++i){
        acc[j][i] = __builtin_amdgcn_mfma_f32_16x16x32_bf16(cah[i], bh[j], acc[j][i], 0, 0, 0);
        acc[j][i] = __builtin_amdgcn_mfma_f32_16x16x32_bf16(cal[i], bh[j], acc[j][i], 0, 0, 0);
      }
    if ((it & 15) == 15){
      #pragma unroll
      for (int j = 0; j < 4; ++j){
        float mm = acc[j][0][0];
        #pragma unroll
        for (int i = 0; i < 2; ++i)
          #pragma unroll
          for (int r = 0; r < 4; ++r) mm = fmaxf(mm, acc[j][i][r]);
        runmax[j] = fmaxf(runmax[j], mm);
        int cls = cb + j*16 + lr;
        if (cls < C_CLS){
          #pragma unroll
          for (int i = 0; i < 2; ++i){
            float4 v = make_float4(acc[j][i][0], acc[j][i][1], acc[j][i][2], acc[j][i][3]);
            *(float4*)(S + (size_t)cls * B_ROWS + b0 + i*16 + lg*4) = v;
          }
        }
        #pragma unroll
        for (int i = 0; i < 2; ++i) acc[j][i] = (v4f){0.f,0.f,0.f,0.f};
      }
    }
    if (it < 63){
      #pragma unroll
      for (int i = 0; i < 2; ++i){ cah[i] = nah[i]; cal[i] = nal[i]; }
    }
  }
  #pragma unroll
  for (int j = 0; j < 4; ++j){
    float m = runmax[j];
    m = fmaxf(m, __shfl_xor(m, 16));
    m = fmaxf(m, __shfl_xor(m, 32));
    int cls = cb + j*16 + lr;
    if (lg == 0 && cls < C_CLS)
      atomicMax(&keys[cls], key_of(m * wn[j*16 + lr]));
  }
}

// ---------------- fused radix pass: LDS hist -> global -> last block selects ----------------
__global__ __launch_bounds__(256) void histsel_kernel(const unsigned* __restrict__ keys, unsigned* __restrict__ hist,
                                                      unsigned* __restrict__ done, Ctrl* __restrict__ ctrl, int shift){
  __shared__ unsigned h[256];
  __shared__ int lastf;
  int t = threadIdx.x;
  h[t] = 0u;
  __syncthreads();
  unsigned himask = (shift >= 24) ? 0u : (0xFFFFFFFFu << (shift + 8));
  unsigned prefix = (shift == 24) ? 0u : (ctrl->prefix & himask);
  for (int c = blockIdx.x * 256 + t; c < C_CLS; c += gridDim.x * 256){
    unsigned k = keys[c];
    if ((k & himask) == prefix) atomicAdd(&h[(k >> shift) & 255], 1u);
  }
  __syncthreads();
  if (h[t]) atomicAdd(&hist[t], h[t]);
  __threadfence();
  if (t == 0) lastf = (atomicAdd(done, 1u) == (unsigned)(gridDim.x - 1));
  __syncthreads();
  if (lastf){
    unsigned v = __hip_atomic_load(&hist[t], __ATOMIC_RELAXED, __HIP_MEMORY_SCOPE_AGENT);
    h[t] = v;
    __syncthreads();
    if (t == 0){
      unsigned need = (shift == 24) ? (unsigned)K_KEEP : ctrl->need;
      unsigned pfx  = (shift == 24) ? 0u : ctrl->prefix;
      unsigned cum = 0; int b;
      for (b = 255; b >= 0; --b){
        if (cum + h[b] >= need) break;
        cum += h[b];
      }
      if (b < 0) b = 0;
      ctrl->prefix = pfx | ((unsigned)b << shift);
      ctrl->need = need - cum;
      __hip_atomic_store(done, 0u, __ATOMIC_RELAXED, __HIP_MEMORY_SCOPE_AGENT);
    }
    __hip_atomic_store(&hist[t], 0u, __ATOMIC_RELAXED, __HIP_MEMORY_SCOPE_AGENT);
  }
}

// ---------------- boundary band around exact screened threshold ----------------
__global__ void band_kernel(const unsigned* __restrict__ keys, const Ctrl* __restrict__ ctrl,
                            int* __restrict__ rlist, int* __restrict__ rcount){
  int c = blockIdx.x * 256 + threadIdx.x;
  if (c >= C_CLS) return;
  unsigned k = keys[c];
  if (k == key_of(2.0f)) return;
  float t = key_inv(ctrl->prefix);
  if (fabsf(key_inv(k) - t) <= BAND){
    int i = atomicAdd(rcount, 1);
    if (i < RMAX) rlist[i] = c;
  }
}

// ---------------- refine via fp32 S candidate rows: exact fp64 dot only where needed ----------------
__global__ __launch_bounds__(256) void refine_kernel(
    const float* __restrict__ tn, const float* __restrict__ w,
    const float* __restrict__ winv, const float* __restrict__ S,
    const int* __restrict__ rlist, const int* __restrict__ rcount,
    unsigned* __restrict__ keys){
  __shared__ float red[256];
  __shared__ double dred[256];
  __shared__ int cand[32];
  __shared__ int ncand;
  int n = *rcount; if (n > RMAX) n = RMAX;
  int t = threadIdx.x;
  for (int i = blockIdx.x; i < n; i += gridDim.x){
    int c = rlist[i];
    const v4f* srow = (const v4f*)(S + (size_t)c * B_ROWS);
    v4f sv = srow[t];
    float m = fmaxf(fmaxf(sv[0],sv[1]), fmaxf(sv[2],sv[3]));
    red[t] = m; __syncthreads();
    for (int off2 = 128; off2; off2 >>= 1){
      if (t < off2) red[t] = fmaxf(red[t], red[t+off2]);
      __syncthreads();
    }
    float thr = red[0] - DELTA;
    if (t == 0) ncand = 0;
    __syncthreads();
    #pragma unroll
    for (int e = 0; e < 4; ++e){
      if (sv[e] >= thr){
        int ci = atomicAdd(&ncand, 1);
        if (ci < 32) cand[ci] = t*4 + e;
      }
    }
    __syncthreads();
    int nc = ncand; if (nc > 32) nc = 32;
    const float* wrow = w + (size_t)c * D_DIM;
    double w0 = (double)wrow[2*t], w1 = (double)wrow[2*t+1];
    double best = -1e300;
    for (int q = 0; q < nc; ++q){
      int b = cand[q];
      const float* tr = tn + (size_t)b * D_DIM;
      double p = fma((double)tr[2*t], w0, (double)tr[2*t+1] * w1);
      dred[t] = p; __syncthreads();
      for (int off2 = 128; off2; off2 >>= 1){
        if (t < off2) dred[t] += dred[t+off2];
        __syncthreads();
      }
      if (t == 0) best = fmax(best, dred[0]);
      __syncthreads();
    }
    if (t == 0) keys[c] = key_of((float)(best * (double)winv[c]));
    __syncthreads();
  }
}

// ---------------- (gt,eq)-pair scan: block sums + last-block mid-scan ----------------
__global__ __launch_bounds__(256) void scanA_kernel(const unsigned* __restrict__ keys, const Ctrl* __restrict__ ctrl,
                                                    uint2* __restrict__ bsum2, unsigned* __restrict__ done2, int nb){
  __shared__ unsigned red[256];
  __shared__ int lastf;
  int t = threadIdx.x;
  unsigned T = ctrl->prefix;
  int base = blockIdx.x * 1024 + t * 4;
  unsigned pack = 0;
  #pragma unroll
  for (int j = 0; j < 4; ++j){
    int c = base + j;
    if (c < C_CLS){
      unsigned k = keys[c];
      if (k > T) pack += 0x10000u;
      else if (k == T) pack += 1u;
    }
  }
  red[t] = pack; __syncthreads();
  for (int off = 128; off; off >>= 1){
    if (t < off) red[t] += red[t + off];
    __syncthreads();
  }
  if (t == 0) bsum2[blockIdx.x] = make_uint2(red[0] >> 16, red[0] & 0xFFFFu);
  __threadfence();
  if (t == 0) lastf = (atomicAdd(done2, 1u) == (unsigned)(gridDim.x - 1));
  __syncthreads();
  if (lastf && t == 0){
    unsigned rg = 0, re = 0;
    for (int i = 0; i < nb; ++i){
      unsigned vx = __hip_atomic_load(&bsum2[i].x, __ATOMIC_RELAXED, __HIP_MEMORY_SCOPE_AGENT);
      unsigned vy = __hip_atomic_load(&bsum2[i].y, __ATOMIC_RELAXED, __HIP_MEMORY_SCOPE_AGENT);
      __hip_atomic_store(&bsum2[i].x, rg, __ATOMIC_RELAXED, __HIP_MEMORY_SCOPE_AGENT);
      __hip_atomic_store(&bsum2[i].y, re, __ATOMIC_RELAXED, __HIP_MEMORY_SCOPE_AGENT);
      rg += vx; re += vy;
    }
    __hip_atomic_store(done2, 0u, __ATOMIC_RELAXED, __HIP_MEMORY_SCOPE_AGENT);
  }
}

// selected = gt | (eq & eqrank<need); pos = gt_excl + min(eq_excl, need); scatter sel ascending
__global__ __launch_bounds__(256) void scanC_kernel(const unsigned* __restrict__ keys, const Ctrl* __restrict__ ctrl,
                                                    const uint2* __restrict__ bsum2, unsigned* __restrict__ pos,
                                                    int* __restrict__ sel){
  __shared__ unsigned ls[256];
  int t = threadIdx.x;
  unsigned T = ctrl->prefix, need = ctrl->need;
  int base = blockIdx.x * 1024 + t * 4;
  unsigned gtv[4], eqv[4], pack = 0;
  #pragma unroll
  for (int j = 0; j < 4; ++j){
    int c = base + j;
    unsigned k = (c < C_CLS) ? keys[c] : 0u;
    gtv[j] = (c < C_CLS && k > T) ? 1u : 0u;
    eqv[j] = (c < C_CLS && k == T) ? 1u : 0u;
    pack += (gtv[j] << 16) + eqv[j];
  }
  ls[t] = pack; __syncthreads();
  for (int off = 1; off < 256; off <<= 1){
    unsigned v = (t >= off) ? ls[t - off] : 0u;
    __syncthreads();
    ls[t] += v;
    __syncthreads();
  }
  unsigned excl = ls[t] - pack;
  uint2 bs = bsum2[blockIdx.x];
  unsigned gtx = bs.x + (excl >> 16);
  unsigned eqx = bs.y + (excl & 0xFFFFu);
  #pragma unroll
  for (int j = 0; j < 4; ++j){
    int c = base + j;
    if (c < C_CLS){
      unsigned p = gtx + (eqx < need ? eqx : need);
      pos[c] = p;
      if (gtv[j] || (eqv[j] && eqx < need)) sel[p] = c;
      gtx += gtv[j]; eqx += eqv[j];
    }
  }
}

__global__ void ntgt_kernel(const int* __restrict__ tgt, const unsigned* __restrict__ pos, float* __restrict__ out){
  int b = blockIdx.x * 256 + threadIdx.x;
  if (b < B_ROWS) out[(size_t)B_ROWS * K_KEEP + b] = (float)pos[tgt[b]];
}

// ---------------- head: gather-transpose-scale from fp32 S ----------------
// Round-5 config (best measured ~235us): 64x64 tile, 8 blocks/CU, full-row lane mapping
// (16 lanes per row) in both phases; grid x = b-tile (fastest) for S-row L2/L3 reuse.
// Round-6's 128-k tile (4 blocks/CU) regressed +23us — occupancy dominates here.
__global__ __launch_bounds__(256) void head_copy_kernel(const float* __restrict__ S, const float* __restrict__ winv,
                                                        const int* __restrict__ sel, float* __restrict__ out){
  __shared__ float tile[64][68];
  __shared__ float wsc[64];
  int k0 = blockIdx.y * 64;
  int b0 = blockIdx.x * 64;
  int tid = threadIdx.x;
  int nk = K_KEEP - k0; if (nk > 64) nk = 64;
  if (tid < 64){
    int kk = k0 + tid;
    wsc[tid] = (kk < K_KEEP) ? winv[sel[kk]] : 0.f;
  }
  int r = tid >> 4, lq = tid & 15;
  #pragma unroll
  for (int itr = 0; itr < 4; ++itr){
    int i = itr * 16 + r;
    if (i < nk){
      int c = sel[k0 + i];
      float4 v = *(const float4*)(S + (size_t)c * B_ROWS + b0 + lq * 4);
      *(float4*)&tile[i][lq * 4] = v;
    }
  }
  __syncthreads();
  #pragma unroll
  for (int itw = 0; itw < 4; ++itw){
    int bb = itw * 16 + r;
    int kk = lq * 4;
    size_t obase = (size_t)(b0 + bb) * K_KEEP + k0;
    if (kk + 3 < nk){
      float4 v = make_float4(tile[kk+0][bb]*wsc[kk+0], tile[kk+1][bb]*wsc[kk+1],
                             tile[kk+2][bb]*wsc[kk+2], tile[kk+3][bb]*wsc[kk+3]);
      *(float4*)(out + obase + kk) = v;
    } else {
      for (int e = 0; e < 4; ++e)
        if (kk + e < nk) out[obase + kk + e] = tile[kk+e][bb]*wsc[kk+e];
    }
  }
}

extern "C" void kernel_launch(void* const* d_in, const int* in_sizes, int n_in,
                              void* d_out, int out_size, void* d_ws, size_t ws_size,
                              hipStream_t stream){
  const float* tensor = (const float*)d_in[0];
  const int*   target = (const int*)d_in[1];
  const float* weight = (const float*)d_in[2];
  float* out = (float*)d_out;

  char* ws = (char*)d_ws;
  size_t off = 0;
  auto carve = [&](size_t bytes) -> char* {
    char* p = ws + off;
    off = (off + bytes + 511) & ~(size_t)511;
    return p;
  };
  float*          tn   = (float*)carve((size_t)B_ROWS * D_DIM * 4);
  unsigned short* tnph = (unsigned short*)carve((size_t)B_ROWS * D_DIM * 2);
  unsigned short* tnpl = (unsigned short*)carve((size_t)B_ROWS * D_DIM * 2);
  float*          winv = (float*)carve((size_t)C_CLS * 4);
  size_t zs = off;  // ---- zeroed region start ----
  unsigned* keys   = (unsigned*)carve((size_t)C_CLS * 4);
  unsigned* hist   = (unsigned*)carve(256 * 4);
  unsigned* done   = (unsigned*)carve(64);
  unsigned* done2  = (unsigned*)carve(64);
  int*      rcount = (int*)carve(64);
  size_t ze = off;  // ---- zeroed region end ----
  Ctrl*     ctrl   = (Ctrl*)carve(64);
  uint2*    bsum2  = (uint2*)carve(128 * 8);
  int*      rlist  = (int*)carve((size_t)RMAX * 4);
  unsigned* pos    = (unsigned*)carve((size_t)C_CLS * 4);
  int*      sel    = (int*)carve((size_t)K_KEEP * 4);
  float*    S      = (float*)carve((size_t)C_CLS * B_ROWS * 4);
  (void)in_sizes; (void)n_in; (void)out_size; (void)ws_size;

  hipMemsetAsync(ws + zs, 0, ze - zs, stream);

  norm_t_kernel<<<B_ROWS, 64, 0, stream>>>(tensor, tn, tnph, tnpl, target, keys);

  mine_kernel<<<(C_CLS + MB_CT - 1) / MB_CT, 512, 0, stream>>>(tnph, tnpl, weight, keys, S, winv);

  // round A: exact screened threshold (4 passes)
  for (int shift = 24; shift >= 0; shift -= 8)
    histsel_kernel<<<128, 256, 0, stream>>>(keys, hist, done, ctrl, shift);

  band_kernel<<<(C_CLS + 255) / 256, 256, 0, stream>>>(keys, ctrl, rlist, rcount);
  refine_kernel<<<2048, 256, 0, stream>>>(tn, weight, winv, S, rlist, rcount, keys);

  // round B: exact threshold on refined keys
  for (int shift = 24; shift >= 0; shift -= 8)
    histsel_kernel<<<128, 256, 0, stream>>>(keys, hist, done, ctrl, shift);

  const int nb = (C_CLS + 1023) / 1024;  // 98
  scanA_kernel<<<nb, 256, 0, stream>>>(keys, ctrl, bsum2, done2, nb);
  scanC_kernel<<<nb, 256, 0, stream>>>(keys, ctrl, bsum2, pos, sel);

  ntgt_kernel<<<(B_ROWS + 255) / 256, 256, 0, stream>>>(target, pos, out);
  head_copy_kernel<<<dim3(B_ROWS / 64, (K_KEEP + 63) / 64), 256, 0, stream>>>(S, winv, sel, out);
}